// Round 3
// baseline (83.821 us; speedup 1.0000x reference)
//
#include <hip/hip_runtime.h>

// TripletMarginLoss, N=512 anchors, D=128, labels in [0,64).
// loss = sum_{valid (i,j,k)} relu(dm[i,j]-dm[i,k]+1) / (count(> eps) + eps)
// valid(i,j,k) <=> j!=i && lab[j]==lab[i] && lab[k]!=lab[i]
//
// Structure: kernel1 materializes dm = E*E^T once (tiled GEMM, 128 blocks)
// instead of every anchor-block re-reading all of E (134 MB -> ~8 MB L2
// traffic). kernel2 (one block per anchor) reads its dm row and sweeps.

#define TN 512
#define TD 128
#define TK4 (TD / 4)          // 32 float4 chunks along K
#define TMARGIN 1.0f
#define TEPS 1e-8f
#define ACC_OFF (TN * TN)     // ws[ACC_OFF..+2] = {sum, count, ticket}

// ---------------- Kernel 1: dm = E * E^T, 32x64 tiles, grid (16,8) ----------
__global__ __launch_bounds__(256) void dm_gemm_kernel(
    const float* __restrict__ emb, float* __restrict__ ws)
{
    // +1 float4 pad: row stride 33 f4 = 132 dwords == 4 mod 32 -> reads spread banks
    __shared__ float4 As[32][TK4 + 1];
    __shared__ float4 Bs[64][TK4 + 1];
    const int t  = threadIdx.x;
    const int bm = blockIdx.x;        // 0..15 (C rows)
    const int bn = blockIdx.y;        // 0..7  (C cols)

    if (bm == 0 && bn == 0 && t < 3) ws[ACC_OFF + t] = 0.0f;  // zero accumulators

    const float4* E4 = (const float4*)emb;   // row stride TK4 float4s

    // stage A tile: 32 rows x 32 f4 (coalesced 512B per 32 lanes)
#pragma unroll
    for (int it = 0; it < 4; ++it) {
        const int g = t + 256 * it;
        const int r = g >> 5, c = g & 31;
        As[r][c] = E4[(bm * 32 + r) * TK4 + c];
    }
    // stage B tile: 64 rows x 32 f4
#pragma unroll
    for (int it = 0; it < 8; ++it) {
        const int g = t + 256 * it;
        const int r = g >> 5, c = g & 31;
        Bs[r][c] = E4[(bn * 64 + r) * TK4 + c];
    }
    __syncthreads();

    // thread -> rows {2ty, 2ty+1}, cols {tx + 16j}. Per wave ty spans only 4
    // values -> A reads are 4-address broadcasts on distinct banks (free);
    // B reads: cols tx+16j -> addr stride 33 f4 -> 2-way bank alias (free).
    const int ty = t >> 4;
    const int tx = t & 15;
    float acc[2][4] = {};
#pragma unroll 8
    for (int k = 0; k < TK4; ++k) {
        const float4 a0 = As[2 * ty + 0][k];
        const float4 a1 = As[2 * ty + 1][k];
#pragma unroll
        for (int j = 0; j < 4; ++j) {
            const float4 b = Bs[tx + 16 * j][k];
            acc[0][j] += a0.x * b.x + a0.y * b.y + a0.z * b.z + a0.w * b.w;
            acc[1][j] += a1.x * b.x + a1.y * b.y + a1.z * b.z + a1.w * b.w;
        }
    }

    float* dm = ws;
#pragma unroll
    for (int r = 0; r < 2; ++r) {
        const int row = bm * 32 + 2 * ty + r;
#pragma unroll
        for (int j = 0; j < 4; ++j)
            dm[row * TN + bn * 64 + tx + 16 * j] = acc[r][j];
    }
}

// ---------------- Kernel 2: per-anchor sweep + global finalize --------------
__global__ __launch_bounds__(256) void triplet_sweep_kernel(
    const float* __restrict__ ws,      // dm + accumulators
    const int* __restrict__ labels,
    float* __restrict__ ws_acc,        // = ws + ACC_OFF (non-const alias)
    float* __restrict__ out)
{
    __shared__ float d[TN];       // dm row for this anchor
    __shared__ float pv[TN];      // positives: d[j] + margin
    __shared__ int   lab[TN];
    __shared__ int   npos;
    __shared__ float red_s[4], red_c[4];

    const int i = blockIdx.x;
    const int t = threadIdx.x;

    for (int j = t; j < TN; j += 256) {
        d[j]   = ws[i * TN + j];
        lab[j] = labels[j];
    }
    if (t == 0) npos = 0;
    __syncthreads();

    const int lab_i = lab[i];

    for (int j = t; j < TN; j += 256) {
        if (j != i && lab[j] == lab_i) {
            int idx = atomicAdd(&npos, 1);
            pv[idx] = d[j] + TMARGIN;
        }
    }
    __syncthreads();

    const int np = npos;
    float lsum = 0.f, lcnt = 0.f;
    for (int k = t; k < TN; k += 256) {
        if (lab[k] != lab_i) {
            const float dn = d[k];
            for (int p = 0; p < np; ++p) {
                const float v = pv[p] - dn;
                if (v > 0.f)   lsum += v;
                if (v > TEPS)  lcnt += 1.f;
            }
        }
    }

#pragma unroll
    for (int off = 32; off > 0; off >>= 1) {
        lsum += __shfl_down(lsum, off);
        lcnt += __shfl_down(lcnt, off);
    }
    const int wave = t >> 6;
    if ((t & 63) == 0) { red_s[wave] = lsum; red_c[wave] = lcnt; }
    __syncthreads();

    if (t == 0) {
        const float bs = red_s[0] + red_s[1] + red_s[2] + red_s[3];
        const float bc = red_c[0] + red_c[1] + red_c[2] + red_c[3];
        atomicAdd(&ws_acc[0], bs);       // device-scope by default
        atomicAdd(&ws_acc[1], bc);
        __threadfence();
        const unsigned tk = atomicAdd((unsigned*)&ws_acc[2], 1u);
        if (tk == gridDim.x - 1) {
            const float s = atomicAdd(&ws_acc[0], 0.f);  // coherent read-back
            const float c = atomicAdd(&ws_acc[1], 0.f);
            out[0] = s / (c + TEPS);
        }
    }
}

extern "C" void kernel_launch(void* const* d_in, const int* in_sizes, int n_in,
                              void* d_out, int out_size, void* d_ws, size_t ws_size,
                              hipStream_t stream) {
    const float* emb  = (const float*)d_in[0];
    const int* labels = (const int*)d_in[1];
    float* out = (float*)d_out;
    float* ws  = (float*)d_ws;

    dim3 grid1(16, 8);
    dm_gemm_kernel<<<grid1, 256, 0, stream>>>(emb, ws);
    triplet_sweep_kernel<<<TN, 256, 0, stream>>>(ws, labels, ws + ACC_OFF, out);
}

// Round 4
// 63.485 us; speedup vs baseline: 1.3203x; 1.3203x over previous
//
#include <hip/hip_runtime.h>

// TripletMarginLoss, N=512 anchors, D=128, labels in [0,64).
// loss = sum_{valid (i,j,k)} relu(dm[i,j]-dm[i,k]+1) / (count(> eps) + eps)
// valid(i,j,k) <=> j!=i && lab[j]==lab[i] && lab[k]!=lab[i]
//
// 3 dispatches, NO global atomics/fences (R3 post-mortem: 512-block
// same-address device-scope atomic+ticket finalize cost ~20 us):
//   1) dm = E*E^T tiled GEMM (256 blocks, 32x32 tiles) -> ws[0..N*N)
//   2) per-anchor sweep -> plain-store {sum,count} at ws[ACC_OFF+2i]
//   3) single-block reduce of 512 pairs -> out

#define TN 512
#define TD 128
#define TK4 (TD / 4)          // 32 float4 chunks along K
#define TMARGIN 1.0f
#define TEPS 1e-8f
#define ACC_OFF (TN * TN)

// ---------------- Kernel 1: dm = E * E^T, 32x32 tiles, grid (16,16) ---------
__global__ __launch_bounds__(256) void dm_gemm_kernel(
    const float* __restrict__ emb, float* __restrict__ ws)
{
    // +1 f4 pad: row stride 33 f4 = 132 dwords == 4 mod 32 -> 2-way max alias (free)
    __shared__ float4 As[32][TK4 + 1];
    __shared__ float4 Bs[32][TK4 + 1];
    const int t  = threadIdx.x;
    const int bm = blockIdx.x;        // 0..15 (C rows)
    const int bn = blockIdx.y;        // 0..15 (C cols)

    const float4* E4 = (const float4*)emb;   // row stride TK4 float4s

#pragma unroll
    for (int it = 0; it < 4; ++it) {
        const int g = t + 256 * it;
        const int r = g >> 5, c = g & 31;
        As[r][c] = E4[(bm * 32 + r) * TK4 + c];
        Bs[r][c] = E4[(bn * 32 + r) * TK4 + c];
    }
    __syncthreads();

    // thread -> rows {2ty, 2ty+1}, cols {tx, tx+16}
    const int ty = t >> 4;
    const int tx = t & 15;
    float acc[2][2] = {};
#pragma unroll 8
    for (int k = 0; k < TK4; ++k) {
        const float4 a0 = As[2 * ty + 0][k];
        const float4 a1 = As[2 * ty + 1][k];
#pragma unroll
        for (int j = 0; j < 2; ++j) {
            const float4 b = Bs[tx + 16 * j][k];
            acc[0][j] += a0.x * b.x + a0.y * b.y + a0.z * b.z + a0.w * b.w;
            acc[1][j] += a1.x * b.x + a1.y * b.y + a1.z * b.z + a1.w * b.w;
        }
    }

    float* dm = ws;
#pragma unroll
    for (int r = 0; r < 2; ++r) {
        const int row = bm * 32 + 2 * ty + r;
#pragma unroll
        for (int j = 0; j < 2; ++j)
            dm[row * TN + bn * 32 + tx + 16 * j] = acc[r][j];
    }
}

// ---------------- Kernel 2: per-anchor sweep, plain-store partials ----------
__global__ __launch_bounds__(256) void triplet_sweep_kernel(
    const float* __restrict__ ws,      // dm
    const int* __restrict__ labels,
    float* __restrict__ part)          // part[2i]=sum_i, part[2i+1]=count_i
{
    __shared__ float d[TN];
    __shared__ float pv[TN];
    __shared__ int   lab[TN];
    __shared__ int   npos;
    __shared__ float red_s[4], red_c[4];

    const int i = blockIdx.x;
    const int t = threadIdx.x;

    for (int j = t; j < TN; j += 256) {
        d[j]   = ws[i * TN + j];
        lab[j] = labels[j];
    }
    if (t == 0) npos = 0;
    __syncthreads();

    const int lab_i = lab[i];

    for (int j = t; j < TN; j += 256) {
        if (j != i && lab[j] == lab_i) {
            int idx = atomicAdd(&npos, 1);   // LDS atomic, cheap
            pv[idx] = d[j] + TMARGIN;
        }
    }
    __syncthreads();

    const int np = npos;
    float lsum = 0.f, lcnt = 0.f;
    for (int k = t; k < TN; k += 256) {
        if (lab[k] != lab_i) {
            const float dn = d[k];
            for (int p = 0; p < np; ++p) {
                const float v = pv[p] - dn;
                if (v > 0.f)   lsum += v;
                if (v > TEPS)  lcnt += 1.f;
            }
        }
    }

#pragma unroll
    for (int off = 32; off > 0; off >>= 1) {
        lsum += __shfl_down(lsum, off);
        lcnt += __shfl_down(lcnt, off);
    }
    const int wave = t >> 6;
    if ((t & 63) == 0) { red_s[wave] = lsum; red_c[wave] = lcnt; }
    __syncthreads();

    if (t == 0) {
        part[2 * i]     = red_s[0] + red_s[1] + red_s[2] + red_s[3];
        part[2 * i + 1] = red_c[0] + red_c[1] + red_c[2] + red_c[3];
    }
}

// ---------------- Kernel 3: reduce 512 pairs, finalize ----------------------
__global__ __launch_bounds__(256) void triplet_reduce_kernel(
    const float* __restrict__ part, float* __restrict__ out)
{
    __shared__ float red_s[4], red_c[4];
    const int t = threadIdx.x;
    float lsum = 0.f, lcnt = 0.f;
#pragma unroll
    for (int r = 0; r < 2; ++r) {
        const int j = t + 256 * r;
        lsum += part[2 * j];
        lcnt += part[2 * j + 1];
    }
#pragma unroll
    for (int off = 32; off > 0; off >>= 1) {
        lsum += __shfl_down(lsum, off);
        lcnt += __shfl_down(lcnt, off);
    }
    const int wave = t >> 6;
    if ((t & 63) == 0) { red_s[wave] = lsum; red_c[wave] = lcnt; }
    __syncthreads();
    if (t == 0) {
        const float s = red_s[0] + red_s[1] + red_s[2] + red_s[3];
        const float c = red_c[0] + red_c[1] + red_c[2] + red_c[3];
        out[0] = s / (c + TEPS);
    }
}

extern "C" void kernel_launch(void* const* d_in, const int* in_sizes, int n_in,
                              void* d_out, int out_size, void* d_ws, size_t ws_size,
                              hipStream_t stream) {
    const float* emb  = (const float*)d_in[0];
    const int* labels = (const int*)d_in[1];
    float* out = (float*)d_out;
    float* ws  = (float*)d_ws;

    dim3 grid1(16, 16);
    dm_gemm_kernel<<<grid1, 256, 0, stream>>>(emb, ws);
    triplet_sweep_kernel<<<TN, 256, 0, stream>>>(ws, labels, ws + ACC_OFF);
    triplet_reduce_kernel<<<1, 256, 0, stream>>>(ws + ACC_OFF, out);
}